// Round 1
// baseline (5983.413 us; speedup 1.0000x reference)
//
#include <hip/hip_runtime.h>
#include <math.h>

#define VOCABN 50000
#define HIDN 512
#define NROWSN 4096
#define RROWS 8

// ---------------- kernel A: bucket rows by cluster ----------------
__global__ __launch_bounds__(256) void group_rows_kernel(
    const int* __restrict__ y, int* __restrict__ cnt, int* __restrict__ lists) {
  int r = blockIdx.x * 256 + threadIdx.x;
  if (r >= NROWSN) return;
  int yy = y[r];
  int k = (yy < 2000) ? 0 : ((yy < 10000) ? 1 : 2);
  int pos = atomicAdd(&cnt[k], 1);
  lists[k * NROWSN + pos] = r;
}

// ---------------- kernel B: fused tail GEMV + online logsumexp ----------------
__global__ __launch_bounds__(256) void tail_kernel(
    const float* __restrict__ x, const int* __restrict__ y,
    const float* __restrict__ cw, const float* __restrict__ cb,
    const float* __restrict__ W, const float* __restrict__ lb,
    const int* __restrict__ cnt, const int* __restrict__ lists,
    float* __restrict__ out) {
  __shared__ float4 xs4[RROWS][HIDN / 4];   // 16 KB staged x rows
  __shared__ float red_m[4][RROWS];
  __shared__ float red_s[4][RROWS];
  __shared__ float ztgt[RROWS];
  __shared__ float cll[RROWS];
  __shared__ int rows_sh[RROWS];
  __shared__ int tgt_sh[RROWS];

  const int k = blockIdx.y;
  const int count = cnt[k];
  const int base = blockIdx.x * RROWS;
  if (base >= count) return;
  const int lo = (k == 0) ? 0 : ((k == 1) ? 2000 : 10000);
  const int hi = (k == 0) ? 2000 : ((k == 1) ? 10000 : VOCABN);
  const int tid = threadIdx.x;
  const int lane = tid & 63;
  const int wv = tid >> 6;

  if (tid < RROWS) {
    int slot = base + tid;
    int r = lists[k * NROWSN + min(slot, count - 1)];  // pad tail with last valid row
    rows_sh[tid] = r;
    tgt_sh[tid] = y[r];  // global column id of target
  }
  __syncthreads();

  // stage x rows into LDS (coalesced float4)
#pragma unroll
  for (int i = 0; i < 4; ++i) {
    int idx = tid + 256 * i;          // 0..1023
    int j = idx >> 7;                 // row slot
    int h4 = idx & 127;               // float4 index within row
    int r = rows_sh[j];
    long xb = ((long)(r >> 10) * 1025 + (r & 1023)) * HIDN;  // x[:, :-1] indexing
    xs4[j][h4] = *reinterpret_cast<const float4*>(x + xb + h4 * 4);
  }
  __syncthreads();

  // per-thread online logsumexp state for 8 rows
  float m[RROWS], s[RROWS];
#pragma unroll
  for (int j = 0; j < RROWS; ++j) { m[j] = -INFINITY; s[j] = 0.f; }

  // column loop: thread owns columns c0, c0+1 within each 512-wide chunk
  for (int cbase = lo; cbase < hi; cbase += 512) {
    int c0 = cbase + 2 * tid;
    if (c0 >= hi) continue;  // hi is even, so c0<hi implies c0+1<hi
    float acc0[RROWS], acc1[RROWS];
#pragma unroll
    for (int j = 0; j < RROWS; ++j) { acc0[j] = 0.f; acc1[j] = 0.f; }
    const float* wp = W + c0;
#pragma unroll 2
    for (int h4 = 0; h4 < HIDN / 4; ++h4) {
      float2 w0 = *reinterpret_cast<const float2*>(wp + (size_t)(4 * h4 + 0) * VOCABN);
      float2 w1 = *reinterpret_cast<const float2*>(wp + (size_t)(4 * h4 + 1) * VOCABN);
      float2 w2 = *reinterpret_cast<const float2*>(wp + (size_t)(4 * h4 + 2) * VOCABN);
      float2 w3 = *reinterpret_cast<const float2*>(wp + (size_t)(4 * h4 + 3) * VOCABN);
#pragma unroll
      for (int j = 0; j < RROWS; ++j) {
        float4 xv = xs4[j][h4];  // broadcast LDS read, no bank conflict
        acc0[j] = fmaf(xv.x, w0.x, acc0[j]);
        acc1[j] = fmaf(xv.x, w0.y, acc1[j]);
        acc0[j] = fmaf(xv.y, w1.x, acc0[j]);
        acc1[j] = fmaf(xv.y, w1.y, acc1[j]);
        acc0[j] = fmaf(xv.z, w2.x, acc0[j]);
        acc1[j] = fmaf(xv.z, w2.y, acc1[j]);
        acc0[j] = fmaf(xv.w, w3.x, acc0[j]);
        acc1[j] = fmaf(xv.w, w3.y, acc1[j]);
      }
    }
    float b0 = lb[c0];
    float b1 = lb[c0 + 1];
#pragma unroll
    for (int j = 0; j < RROWS; ++j) {
      float z0 = acc0[j] + b0;
      float z1 = acc1[j] + b1;
      if (c0 == tgt_sh[j]) ztgt[j] = z0;          // unique writer per (row)
      if (c0 + 1 == tgt_sh[j]) ztgt[j] = z1;
      float zm = fmaxf(z0, z1);
      if (zm > m[j]) {
        s[j] = s[j] * __expf(m[j] - zm) + __expf(z0 - zm) + __expf(z1 - zm);
        m[j] = zm;
      } else {
        s[j] += __expf(z0 - m[j]) + __expf(z1 - m[j]);
      }
    }
  }

  // wave-level (m,s) reduction
#pragma unroll
  for (int j = 0; j < RROWS; ++j) {
    float mm = m[j], ss = s[j];
#pragma unroll
    for (int off = 32; off; off >>= 1) {
      float m2 = __shfl_down(mm, off, 64);
      float s2 = __shfl_down(ss, off, 64);
      float M = fmaxf(mm, m2);
      float e1 = (mm == -INFINITY) ? 0.f : __expf(mm - M);
      float e2 = (m2 == -INFINITY) ? 0.f : __expf(m2 - M);
      ss = ss * e1 + s2 * e2;
      mm = M;
    }
    if (lane == 0) { red_m[wv][j] = mm; red_s[wv][j] = ss; }
  }

  // cluster log-softmax per row (wave wv handles rows wv, wv+4), from staged x
  for (int jj = wv; jj < RROWS; jj += 4) {
    const float* xr = reinterpret_cast<const float*>(&xs4[jj][0]);
    float a0 = 0.f, a1 = 0.f, a2 = 0.f;
    int hbase = lane * 8;
#pragma unroll
    for (int u = 0; u < 8; ++u) {
      float xv = xr[hbase + u];
      a0 = fmaf(xv, cw[(hbase + u) * 3 + 0], a0);
      a1 = fmaf(xv, cw[(hbase + u) * 3 + 1], a1);
      a2 = fmaf(xv, cw[(hbase + u) * 3 + 2], a2);
    }
#pragma unroll
    for (int off = 32; off; off >>= 1) {
      a0 += __shfl_xor(a0, off, 64);
      a1 += __shfl_xor(a1, off, 64);
      a2 += __shfl_xor(a2, off, 64);
    }
    if (lane == 0) {
      a0 += cb[0]; a1 += cb[1]; a2 += cb[2];
      float m3 = fmaxf(a0, fmaxf(a1, a2));
      float lse = m3 + logf(__expf(a0 - m3) + __expf(a1 - m3) + __expf(a2 - m3));
      float sel = (k == 0) ? a0 : ((k == 1) ? a1 : a2);
      cll[jj] = sel - lse;
    }
  }
  __syncthreads();

  // final: combine 4 wave partials, add target logit and cluster ll
  if (tid < RROWS) {
    int slot = base + tid;
    if (slot < count) {
      float mm = red_m[0][tid], ss = red_s[0][tid];
#pragma unroll
      for (int w = 1; w < 4; ++w) {
        float m2 = red_m[w][tid], s2 = red_s[w][tid];
        float M = fmaxf(mm, m2);
        float e1 = (mm == -INFINITY) ? 0.f : __expf(mm - M);
        float e2 = (m2 == -INFINITY) ? 0.f : __expf(m2 - M);
        ss = ss * e1 + s2 * e2;
        mm = M;
      }
      float lse_tail = mm + logf(ss);
      float nll = -(cll[tid] + ztgt[tid] - lse_tail);
      out[rows_sh[tid]] = nll;
    }
  }
}

extern "C" void kernel_launch(void* const* d_in, const int* in_sizes, int n_in,
                              void* d_out, int out_size, void* d_ws, size_t ws_size,
                              hipStream_t stream) {
  (void)in_sizes; (void)n_in; (void)out_size; (void)ws_size;
  const float* x  = (const float*)d_in[0];
  const int*   y  = (const int*)d_in[1];
  const float* cw = (const float*)d_in[2];
  const float* cb = (const float*)d_in[3];
  const float* W  = (const float*)d_in[4];
  const float* lb = (const float*)d_in[5];
  float* out = (float*)d_out;

  int* cnt = (int*)d_ws;                       // 3 counters (16 B reserved)
  int* lists = (int*)((char*)d_ws + 16);       // 3 * 4096 row ids

  hipMemsetAsync(cnt, 0, 16, stream);
  group_rows_kernel<<<(NROWSN + 255) / 256, 256, 0, stream>>>(y, cnt, lists);
  dim3 grid((NROWSN + RROWS - 1) / RROWS, 3);
  tail_kernel<<<grid, 256, 0, stream>>>(x, y, cw, cb, W, lb, cnt, lists, out);
}

// Round 2
// 1002.418 us; speedup vs baseline: 5.9690x; 5.9690x over previous
//
#include <hip/hip_runtime.h>
#include <math.h>

#define VOCABN 50000
#define HIDN 512
#define NROWS 4096
#define MTILE 64
#define FPB 64     // 16-col fragments per n-chunk
#define MAXNS 40

typedef __attribute__((ext_vector_type(8))) short bf16x8;
typedef __attribute__((ext_vector_type(4))) float f32x4;
typedef __attribute__((ext_vector_type(4))) unsigned u32x4;

// pack two fp32 into 2 bf16 (truncate) in one v_perm
__device__ __forceinline__ unsigned pk2(float hi, float lo) {
  return __builtin_amdgcn_perm(__builtin_bit_cast(unsigned, hi),
                               __builtin_bit_cast(unsigned, lo),
                               0x07060302u);
}

// ---------------- kernel A: bucket rows by cluster ----------------
__global__ __launch_bounds__(256) void group_rows_kernel(
    const int* __restrict__ y, int* __restrict__ cnt, int* __restrict__ lists) {
  int r = blockIdx.x * 256 + threadIdx.x;
  if (r >= NROWS) return;
  int yy = y[r];
  int k = (yy < 2000) ? 0 : ((yy < 10000) ? 1 : 2);
  int pos = atomicAdd(&cnt[k], 1);
  lists[k * NROWS + pos] = r;
}

// ---------------- kernel B: cluster-head log-softmax (per row) ----------------
__global__ __launch_bounds__(256) void cll_kernel(
    const float* __restrict__ x, const int* __restrict__ y,
    const float* __restrict__ cw, const float* __restrict__ cb,
    float* __restrict__ cll) {
  int wv = threadIdx.x >> 6, lane = threadIdx.x & 63;
  int row = blockIdx.x * 4 + wv;
  if (row >= NROWS) return;
  const float* xr = x + (size_t)((row >> 10) * 1025 + (row & 1023)) * HIDN;
  float4 v0 = *reinterpret_cast<const float4*>(xr + lane * 8);
  float4 v1 = *reinterpret_cast<const float4*>(xr + lane * 8 + 4);
  float xs[8] = {v0.x, v0.y, v0.z, v0.w, v1.x, v1.y, v1.z, v1.w};
  float a0 = 0.f, a1 = 0.f, a2 = 0.f;
#pragma unroll
  for (int u = 0; u < 8; ++u) {
    int h = lane * 8 + u;
    a0 = fmaf(xs[u], cw[h * 3 + 0], a0);
    a1 = fmaf(xs[u], cw[h * 3 + 1], a1);
    a2 = fmaf(xs[u], cw[h * 3 + 2], a2);
  }
#pragma unroll
  for (int off = 32; off; off >>= 1) {
    a0 += __shfl_xor(a0, off, 64);
    a1 += __shfl_xor(a1, off, 64);
    a2 += __shfl_xor(a2, off, 64);
  }
  if (lane == 0) {
    a0 += cb[0]; a1 += cb[1]; a2 += cb[2];
    float m3 = fmaxf(a0, fmaxf(a1, a2));
    float lse = m3 + __logf(__expf(a0 - m3) + __expf(a1 - m3) + __expf(a2 - m3));
    int yy = y[row];
    float sel = (yy < 2000) ? a0 : ((yy < 10000) ? a1 : a2);
    cll[row] = sel - lse;
  }
}

// ---------------- kernel C: MFMA tail logits + online LSE partials ----------------
__global__ __launch_bounds__(256, 2) void tail_mfma_kernel(
    const float* __restrict__ x, const int* __restrict__ y,
    const float* __restrict__ W, const float* __restrict__ lb,
    const int* __restrict__ cnt, const int* __restrict__ lists,
    float* __restrict__ pm, float* __restrict__ ps, float* __restrict__ ztgt) {
  const int k = blockIdx.z;
  const int NSk = (k == 0) ? 2 : ((k == 1) ? 8 : 40);
  const int ns = blockIdx.y;
  if (ns >= NSk) return;
  const int count = cnt[k];
  const int base = blockIdx.x * MTILE;
  if (base >= count) return;
  const int LOk   = (k == 0) ? 0 : ((k == 1) ? 2000 : 10000);
  const int NFRAG = ((k == 0) ? 2000 : ((k == 1) ? 8000 : 40000)) >> 4;
  const int NSOFF = (k == 0) ? 0 : ((k == 1) ? 2 : 10);
  const int flo = ns * FPB;
  const int fhi = min(NFRAG, flo + FPB);

  const int tid = threadIdx.x;
  const int lane = tid & 63;
  const int wv = tid >> 6;
  const int l15 = lane & 15;
  const int lg = lane >> 4;

  __shared__ int rows_sh[MTILE];
  __shared__ int tgt_sh[MTILE];
  __shared__ float redm[4][MTILE];
  __shared__ float reds[4][MTILE];

  if (tid < MTILE) {
    int r = lists[k * NROWS + min(base + tid, count - 1)];
    rows_sh[tid] = r;
    tgt_sh[tid] = y[r];
  }
  __syncthreads();

  // per-lane A row pointers (float4 units), k-group offset folded in
  const float4* xq[4];
#pragma unroll
  for (int mf = 0; mf < 4; ++mf) {
    int r = rows_sh[mf * 16 + l15];
    xq[mf] = reinterpret_cast<const float4*>(
                 x + (size_t)((r >> 10) * 1025 + (r & 1023)) * HIDN) + lg * 2;
  }
  int tc[16];
#pragma unroll
  for (int mf = 0; mf < 4; ++mf)
#pragma unroll
    for (int r = 0; r < 4; ++r) tc[mf * 4 + r] = tgt_sh[mf * 16 + lg * 4 + r];

  float mM[16], sS[16];
#pragma unroll
  for (int i = 0; i < 16; ++i) { mM[i] = -INFINITY; sS[i] = 0.f; }

  const unsigned kg_off = (unsigned)(lg * 8) * VOCABN;

  // wave wv owns fragments flo+wv, flo+wv+4, ... processed in groups of 4
  for (int f0 = flo + wv; f0 < fhi; f0 += 16) {
    int fc[4];
    bool val[4];
    unsigned vb[4];
    float biasv[4];
#pragma unroll
    for (int c = 0; c < 4; ++c) {
      int f = f0 + 4 * c;
      val[c] = (f < fhi);
      if (!val[c]) f = fhi - 1;   // clamp: redundant compute, skipped in epilogue
      fc[c] = f;
      unsigned col = (unsigned)(LOk + f * 16 + l15);
      vb[c] = kg_off + col;
      biasv[c] = lb[col];
    }
    f32x4 acc[4][4];
#pragma unroll
    for (int c = 0; c < 4; ++c)
#pragma unroll
      for (int mf = 0; mf < 4; ++mf) acc[c][mf] = (f32x4){0.f, 0.f, 0.f, 0.f};

    for (int ks = 0; ks < 16; ++ks) {
      // A fragments: 4 m-frags, 8 k-contiguous fp32 each -> bf16x8
      bf16x8 afr[4];
#pragma unroll
      for (int mf = 0; mf < 4; ++mf) {
        float4 x0 = xq[mf][ks * 8];
        float4 x1 = xq[mf][ks * 8 + 1];
        u32x4 d;
        d.x = pk2(x0.y, x0.x);
        d.y = pk2(x0.w, x0.z);
        d.z = pk2(x1.y, x1.x);
        d.w = pk2(x1.w, x1.z);
        afr[mf] = __builtin_bit_cast(bf16x8, d);
      }
      const float* Wk = W + (size_t)ks * 32 * VOCABN;  // wave-uniform base
#pragma unroll
      for (int c = 0; c < 4; ++c) {
        float w0 = Wk[vb[c]];
        float w1 = (Wk + 1 * VOCABN)[vb[c]];
        float w2 = (Wk + 2 * VOCABN)[vb[c]];
        float w3 = (Wk + 3 * VOCABN)[vb[c]];
        float w4 = (Wk + 4 * VOCABN)[vb[c]];
        float w5 = (Wk + 5 * VOCABN)[vb[c]];
        float w6 = (Wk + 6 * VOCABN)[vb[c]];
        float w7 = (Wk + 7 * VOCABN)[vb[c]];
        u32x4 d;
        d.x = pk2(w1, w0);
        d.y = pk2(w3, w2);
        d.z = pk2(w5, w4);
        d.w = pk2(w7, w6);
        bf16x8 bfr = __builtin_bit_cast(bf16x8, d);
#pragma unroll
        for (int mf = 0; mf < 4; ++mf)
          acc[c][mf] = __builtin_amdgcn_mfma_f32_16x16x32_bf16(
              afr[mf], bfr, acc[c][mf], 0, 0, 0);
      }
    }

    // epilogue: bias add, target capture, online LSE per owned row
#pragma unroll
    for (int c = 0; c < 4; ++c) {
      if (!val[c]) continue;  // wave-uniform
      int col = LOk + fc[c] * 16 + l15;
#pragma unroll
      for (int mf = 0; mf < 4; ++mf)
#pragma unroll
        for (int r = 0; r < 4; ++r) {
          float z = acc[c][mf][r] + biasv[c];
          int i = mf * 4 + r;
          if (tc[i] == col) ztgt[rows_sh[mf * 16 + lg * 4 + r]] = z;
          float nm = fmaxf(mM[i], z);
          sS[i] = sS[i] * __expf(mM[i] - nm) + __expf(z - nm);
          mM[i] = nm;
        }
    }
  }

  // reduce (m,s) across the 16 column-residue lanes
#pragma unroll
  for (int i = 0; i < 16; ++i) {
    float m = mM[i], s = sS[i];
#pragma unroll
    for (int off = 1; off < 16; off <<= 1) {
      float m2 = __shfl_xor(m, off, 64);
      float s2 = __shfl_xor(s, off, 64);
      float nm = fmaxf(m, m2);
      s = s * __expf(m - nm) + s2 * __expf(m2 - nm);
      m = nm;
    }
    mM[i] = m; sS[i] = s;
  }
  if (l15 == 0) {
#pragma unroll
    for (int mf = 0; mf < 4; ++mf)
#pragma unroll
      for (int r = 0; r < 4; ++r) {
        redm[wv][mf * 16 + lg * 4 + r] = mM[mf * 4 + r];
        reds[wv][mf * 16 + lg * 4 + r] = sS[mf * 4 + r];
      }
  }
  __syncthreads();
  // merge 4 waves, write partials
  if (tid < MTILE) {
    float m = redm[0][tid], s = reds[0][tid];
#pragma unroll
    for (int w = 1; w < 4; ++w) {
      float m2 = redm[w][tid], s2 = reds[w][tid];
      float nm = fmaxf(m, m2);
      s = s * __expf(m - nm) + s2 * __expf(m2 - nm);
      m = nm;
    }
    pm[(NSOFF + ns) * NROWS + base + tid] = m;
    ps[(NSOFF + ns) * NROWS + base + tid] = s;
  }
}

// ---------------- kernel D: merge partials -> nll ----------------
__global__ __launch_bounds__(256) void combine_kernel(
    const int* __restrict__ cnt, const int* __restrict__ lists,
    const float* __restrict__ pm, const float* __restrict__ ps,
    const float* __restrict__ cll, const float* __restrict__ ztgt,
    float* __restrict__ out) {
  int t = blockIdx.x * 256 + threadIdx.x;
  if (t >= 3 * NROWS) return;
  int k = t / NROWS, slot = t % NROWS;
  if (slot >= cnt[k]) return;
  int row = lists[k * NROWS + slot];
  int NSk = (k == 0) ? 2 : ((k == 1) ? 8 : 40);
  int NSO = (k == 0) ? 0 : ((k == 1) ? 2 : 10);
  float m = -INFINITY, s = 0.f;
  for (int ns = 0; ns < NSk; ++ns) {
    float m2 = pm[(NSO + ns) * NROWS + slot];
    float s2 = ps[(NSO + ns) * NROWS + slot];
    float nm = fmaxf(m, m2);
    s = s * __expf(m - nm) + s2 * __expf(m2 - nm);
    m = nm;
  }
  float lse = m + __logf(s);
  out[row] = -(cll[row] + ztgt[row] - lse);
}

extern "C" void kernel_launch(void* const* d_in, const int* in_sizes, int n_in,
                              void* d_out, int out_size, void* d_ws, size_t ws_size,
                              hipStream_t stream) {
  (void)in_sizes; (void)n_in; (void)out_size; (void)ws_size;
  const float* x  = (const float*)d_in[0];
  const int*   y  = (const int*)d_in[1];
  const float* cw = (const float*)d_in[2];
  const float* cb = (const float*)d_in[3];
  const float* W  = (const float*)d_in[4];
  const float* lb = (const float*)d_in[5];
  float* out = (float*)d_out;

  char* ws = (char*)d_ws;
  int* cnt     = (int*)(ws + 0);          // 16 B
  int* lists   = (int*)(ws + 16);         // 3*4096*4 = 49152 B
  float* cll   = (float*)(ws + 49168);    // 16384 B
  float* ztgt  = (float*)(ws + 65552);    // 16384 B
  float* pm    = (float*)(ws + 81936);    // 50*4096*4 = 819200 B
  float* ps    = (float*)(ws + 901136);   // 819200 B  -> total 1720336 B

  hipMemsetAsync(cnt, 0, 16, stream);
  group_rows_kernel<<<(NROWS + 255) / 256, 256, 0, stream>>>(y, cnt, lists);
  cll_kernel<<<NROWS / 4, 256, 0, stream>>>(x, y, cw, cb, cll);
  dim3 tg(NROWS / MTILE, MAXNS, 3);
  tail_mfma_kernel<<<tg, 256, 0, stream>>>(x, y, W, lb, cnt, lists, pm, ps, ztgt);
  combine_kernel<<<(3 * NROWS + 255) / 256, 256, 0, stream>>>(cnt, lists, pm, ps, cll, ztgt, out);
}

// Round 3
// 809.282 us; speedup vs baseline: 7.3935x; 1.2387x over previous
//
#include <hip/hip_runtime.h>
#include <math.h>

#define VOCABN 50000
#define HIDN 512
#define NROWS 4096
#define MTILE 64
#define FPB 64       // 16-col fragments per n-chunk
#define MAXNS 40
#define NFRAG_ALL 3125   // 50000/16

typedef __attribute__((ext_vector_type(8))) short bf16x8;
typedef __attribute__((ext_vector_type(4))) float f32x4;
typedef __attribute__((ext_vector_type(4))) unsigned u32x4;

// pack two fp32 into 2 bf16 (truncate): result = {lo.bf16 in [15:0], hi.bf16 in [31:16]}
__device__ __forceinline__ unsigned pk2(float hi, float lo) {
  return __builtin_amdgcn_perm(__builtin_bit_cast(unsigned, hi),
                               __builtin_bit_cast(unsigned, lo),
                               0x07060302u);
}

// ---------------- kernel A: bucket rows by cluster ----------------
__global__ __launch_bounds__(256) void group_rows_kernel(
    const int* __restrict__ y, int* __restrict__ cnt, int* __restrict__ lists) {
  int r = blockIdx.x * 256 + threadIdx.x;
  if (r >= NROWS) return;
  int yy = y[r];
  int k = (yy < 2000) ? 0 : ((yy < 10000) ? 1 : 2);
  int pos = atomicAdd(&cnt[k], 1);
  lists[k * NROWS + pos] = r;
}

// ---------------- kernel B: cluster-head log-softmax (per row) ----------------
__global__ __launch_bounds__(256) void cll_kernel(
    const float* __restrict__ x, const int* __restrict__ y,
    const float* __restrict__ cw, const float* __restrict__ cb,
    float* __restrict__ cll) {
  int wv = threadIdx.x >> 6, lane = threadIdx.x & 63;
  int row = blockIdx.x * 4 + wv;
  if (row >= NROWS) return;
  const float* xr = x + (size_t)((row >> 10) * 1025 + (row & 1023)) * HIDN;
  float4 v0 = *reinterpret_cast<const float4*>(xr + lane * 8);
  float4 v1 = *reinterpret_cast<const float4*>(xr + lane * 8 + 4);
  float xs[8] = {v0.x, v0.y, v0.z, v0.w, v1.x, v1.y, v1.z, v1.w};
  float a0 = 0.f, a1 = 0.f, a2 = 0.f;
#pragma unroll
  for (int u = 0; u < 8; ++u) {
    int h = lane * 8 + u;
    a0 = fmaf(xs[u], cw[h * 3 + 0], a0);
    a1 = fmaf(xs[u], cw[h * 3 + 1], a1);
    a2 = fmaf(xs[u], cw[h * 3 + 2], a2);
  }
#pragma unroll
  for (int off = 32; off; off >>= 1) {
    a0 += __shfl_xor(a0, off, 64);
    a1 += __shfl_xor(a1, off, 64);
    a2 += __shfl_xor(a2, off, 64);
  }
  if (lane == 0) {
    a0 += cb[0]; a1 += cb[1]; a2 += cb[2];
    float m3 = fmaxf(a0, fmaxf(a1, a2));
    float lse = m3 + __logf(__expf(a0 - m3) + __expf(a1 - m3) + __expf(a2 - m3));
    int yy = y[row];
    float sel = (yy < 2000) ? a0 : ((yy < 10000) ? a1 : a2);
    cll[row] = sel - lse;
  }
}

// ---------------- kernel W: pack W fp32 [k][col] -> bf16 fragment order ----------------
// entry e = ((f*16 + ks)*64 + lane) holds {W[ks*32+(lane>>4)*8+j][f*16+(lane&15)], j=0..7}
__global__ __launch_bounds__(256) void packW_kernel(
    const float* __restrict__ W, u32x4* __restrict__ Wb) {
  int e = blockIdx.x * 256 + threadIdx.x;
  int lane = e & 63;
  int ks = (e >> 6) & 15;
  int f = e >> 10;
  if (f >= NFRAG_ALL) return;
  int col = f * 16 + (lane & 15);
  int k0 = ks * 32 + ((lane >> 4) & 3) * 8;
  const float* wp = W + (size_t)k0 * VOCABN + col;
  float w0 = wp[0 * VOCABN];
  float w1 = wp[1 * VOCABN];
  float w2 = wp[2 * VOCABN];
  float w3 = wp[3 * VOCABN];
  float w4 = wp[4 * VOCABN];
  float w5 = wp[5 * VOCABN];
  float w6 = wp[6 * VOCABN];
  float w7 = wp[7 * VOCABN];
  u32x4 d;
  d.x = pk2(w1, w0);
  d.y = pk2(w3, w2);
  d.z = pk2(w5, w4);
  d.w = pk2(w7, w6);
  Wb[e] = d;
}

// ---------------- kernel C (fast): MFMA tail, packed B from Wb + A staged in LDS ----------------
__global__ __launch_bounds__(256, 2) void tail_mfma_packed(
    const float* __restrict__ x, const int* __restrict__ y,
    const u32x4* __restrict__ Wb, const float* __restrict__ lb,
    const int* __restrict__ cnt, const int* __restrict__ lists,
    float* __restrict__ pm, float* __restrict__ ps, float* __restrict__ ztgt) {
  const int k = blockIdx.z;
  const int NSk = (k == 0) ? 2 : ((k == 1) ? 8 : 40);
  const int ns = blockIdx.y;
  if (ns >= NSk) return;
  const int count = cnt[k];
  const int base = blockIdx.x * MTILE;
  if (base >= count) return;
  const int LOk   = (k == 0) ? 0 : ((k == 1) ? 2000 : 10000);
  const int FRAG0 = LOk >> 4;
  const int NFRAG = ((k == 0) ? 2000 : ((k == 1) ? 8000 : 40000)) >> 4;
  const int NSOFF = (k == 0) ? 0 : ((k == 1) ? 2 : 10);
  const int flo = ns * FPB;
  const int fhi = min(NFRAG, flo + FPB);

  const int tid = threadIdx.x;
  const int lane = tid & 63;
  const int wv = tid >> 6;
  const int l15 = lane & 15;
  const int lg = lane >> 4;

  __shared__ u32x4 As[16 * 4 * 64];   // 64 KB, [ks][mf][lane]
  __shared__ int rows_sh[MTILE];
  __shared__ int tgt_sh[MTILE];
  __shared__ float redm[4][MTILE];
  __shared__ float reds[4][MTILE];

  if (tid < MTILE) {
    int r = lists[k * NROWS + min(base + tid, count - 1)];
    rows_sh[tid] = r;
    tgt_sh[tid] = y[r];
  }
  __syncthreads();

  // stage A tile into LDS in fragment order, bf16: entry e=(ks,mf,lane)
#pragma unroll
  for (int i = 0; i < 16; ++i) {
    int e = tid + 256 * i;
    int ln = e & 63, mf = (e >> 6) & 3, ks = e >> 8;
    int r = rows_sh[mf * 16 + (ln & 15)];
    const float* xr = x + (size_t)((r >> 10) * 1025 + (r & 1023)) * HIDN
                        + ks * 32 + ((ln >> 4) & 3) * 8;
    float4 x0 = *reinterpret_cast<const float4*>(xr);
    float4 x1 = *reinterpret_cast<const float4*>(xr + 4);
    u32x4 d;
    d.x = pk2(x0.y, x0.x);
    d.y = pk2(x0.w, x0.z);
    d.z = pk2(x1.y, x1.x);
    d.w = pk2(x1.w, x1.z);
    As[e] = d;
  }
  __syncthreads();

  int tc[16];
#pragma unroll
  for (int mf = 0; mf < 4; ++mf)
#pragma unroll
    for (int r = 0; r < 4; ++r) tc[mf * 4 + r] = tgt_sh[mf * 16 + lg * 4 + r];

  float mM[16], sS[16];
#pragma unroll
  for (int i = 0; i < 16; ++i) { mM[i] = -INFINITY; sS[i] = 0.f; }

  for (int f0 = flo + wv; f0 < fhi; f0 += 16) {
    int fc[4];
    bool val[4];
    const u32x4* bp[4];
    float biasv[4];
#pragma unroll
    for (int c = 0; c < 4; ++c) {
      int f = f0 + 4 * c;
      val[c] = (f < fhi);
      if (!val[c]) f = fhi - 1;
      fc[c] = f;
      bp[c] = Wb + ((size_t)(FRAG0 + f) * 16) * 64 + lane;
      biasv[c] = lb[LOk + f * 16 + l15];
    }
    f32x4 acc[4][4];
#pragma unroll
    for (int c = 0; c < 4; ++c)
#pragma unroll
      for (int mf = 0; mf < 4; ++mf) acc[c][mf] = (f32x4){0.f, 0.f, 0.f, 0.f};

#pragma unroll
    for (int ks = 0; ks < 16; ++ks) {
      bf16x8 afr[4];
#pragma unroll
      for (int mf = 0; mf < 4; ++mf)
        afr[mf] = __builtin_bit_cast(bf16x8, As[(ks * 4 + mf) * 64 + lane]);
#pragma unroll
      for (int c = 0; c < 4; ++c) {
        bf16x8 bfr = __builtin_bit_cast(bf16x8, bp[c][ks * 64]);
#pragma unroll
        for (int mf = 0; mf < 4; ++mf)
          acc[c][mf] = __builtin_amdgcn_mfma_f32_16x16x32_bf16(
              afr[mf], bfr, acc[c][mf], 0, 0, 0);
      }
    }

    // epilogue: bias, target capture, online LSE
#pragma unroll
    for (int c = 0; c < 4; ++c) {
      if (!val[c]) continue;  // wave-uniform
      int col = LOk + fc[c] * 16 + l15;
#pragma unroll
      for (int mf = 0; mf < 4; ++mf)
#pragma unroll
        for (int r = 0; r < 4; ++r) {
          float z = acc[c][mf][r] + biasv[c];
          int i = mf * 4 + r;
          if (tc[i] == col) ztgt[rows_sh[mf * 16 + lg * 4 + r]] = z;
          float nm = fmaxf(mM[i], z);
          sS[i] = sS[i] * __expf(mM[i] - nm) + __expf(z - nm);
          mM[i] = nm;
        }
    }
  }

  // reduce (m,s) across the 16 column-residue lanes
#pragma unroll
  for (int i = 0; i < 16; ++i) {
    float m = mM[i], s = sS[i];
#pragma unroll
    for (int off = 1; off < 16; off <<= 1) {
      float m2 = __shfl_xor(m, off, 64);
      float s2 = __shfl_xor(s, off, 64);
      float nm = fmaxf(m, m2);
      s = s * __expf(m - nm) + s2 * __expf(m2 - nm);
      m = nm;
    }
    mM[i] = m; sS[i] = s;
  }
  if (l15 == 0) {
#pragma unroll
    for (int mf = 0; mf < 4; ++mf)
#pragma unroll
      for (int r = 0; r < 4; ++r) {
        redm[wv][mf * 16 + lg * 4 + r] = mM[mf * 4 + r];
        reds[wv][mf * 16 + lg * 4 + r] = sS[mf * 4 + r];
      }
  }
  __syncthreads();
  if (tid < MTILE) {
    float m = redm[0][tid], s = reds[0][tid];
#pragma unroll
    for (int w = 1; w < 4; ++w) {
      float m2 = redm[w][tid], s2 = reds[w][tid];
      float nm = fmaxf(m, m2);
      s = s * __expf(m - nm) + s2 * __expf(m2 - nm);
      m = nm;
    }
    pm[(NSOFF + ns) * NROWS + base + tid] = m;
    ps[(NSOFF + ns) * NROWS + base + tid] = s;
  }
}

// ---------------- kernel C (fallback, round-2 proven) ----------------
__global__ __launch_bounds__(256, 2) void tail_mfma_fb(
    const float* __restrict__ x, const int* __restrict__ y,
    const float* __restrict__ W, const float* __restrict__ lb,
    const int* __restrict__ cnt, const int* __restrict__ lists,
    float* __restrict__ pm, float* __restrict__ ps, float* __restrict__ ztgt) {
  const int k = blockIdx.z;
  const int NSk = (k == 0) ? 2 : ((k == 1) ? 8 : 40);
  const int ns = blockIdx.y;
  if (ns >= NSk) return;
  const int count = cnt[k];
  const int base = blockIdx.x * MTILE;
  if (base >= count) return;
  const int LOk   = (k == 0) ? 0 : ((k == 1) ? 2000 : 10000);
  const int NFRAG = ((k == 0) ? 2000 : ((k == 1) ? 8000 : 40000)) >> 4;
  const int NSOFF = (k == 0) ? 0 : ((k == 1) ? 2 : 10);
  const int flo = ns * FPB;
  const int fhi = min(NFRAG, flo + FPB);
  const int tid = threadIdx.x;
  const int lane = tid & 63;
  const int wv = tid >> 6;
  const int l15 = lane & 15;
  const int lg = lane >> 4;

  __shared__ int rows_sh[MTILE];
  __shared__ int tgt_sh[MTILE];
  __shared__ float redm[4][MTILE];
  __shared__ float reds[4][MTILE];

  if (tid < MTILE) {
    int r = lists[k * NROWS + min(base + tid, count - 1)];
    rows_sh[tid] = r;
    tgt_sh[tid] = y[r];
  }
  __syncthreads();

  const float4* xq[4];
#pragma unroll
  for (int mf = 0; mf < 4; ++mf) {
    int r = rows_sh[mf * 16 + l15];
    xq[mf] = reinterpret_cast<const float4*>(
                 x + (size_t)((r >> 10) * 1025 + (r & 1023)) * HIDN) + lg * 2;
  }
  int tc[16];
#pragma unroll
  for (int mf = 0; mf < 4; ++mf)
#pragma unroll
    for (int r = 0; r < 4; ++r) tc[mf * 4 + r] = tgt_sh[mf * 16 + lg * 4 + r];

  float mM[16], sS[16];
#pragma unroll
  for (int i = 0; i < 16; ++i) { mM[i] = -INFINITY; sS[i] = 0.f; }
  const unsigned kg_off = (unsigned)(lg * 8) * VOCABN;

  for (int f0 = flo + wv; f0 < fhi; f0 += 16) {
    int fc[4];
    bool val[4];
    unsigned vb[4];
    float biasv[4];
#pragma unroll
    for (int c = 0; c < 4; ++c) {
      int f = f0 + 4 * c;
      val[c] = (f < fhi);
      if (!val[c]) f = fhi - 1;
      fc[c] = f;
      unsigned col = (unsigned)(LOk + f * 16 + l15);
      vb[c] = kg_off + col;
      biasv[c] = lb[col];
    }
    f32x4 acc[4][4];
#pragma unroll
    for (int c = 0; c < 4; ++c)
#pragma unroll
      for (int mf = 0; mf < 4; ++mf) acc[c][mf] = (f32x4){0.f, 0.f, 0.f, 0.f};

    for (int ks = 0; ks < 16; ++ks) {
      bf16x8 afr[4];
#pragma unroll
      for (int mf = 0; mf < 4; ++mf) {
        float4 x0 = xq[mf][ks * 8];
        float4 x1 = xq[mf][ks * 8 + 1];
        u32x4 d;
        d.x = pk2(x0.y, x0.x);
        d.y = pk2(x0.w, x0.z);
        d.z = pk2(x1.y, x1.x);
        d.w = pk2(x1.w, x1.z);
        afr[mf] = __builtin_bit_cast(bf16x8, d);
      }
      const float* Wk = W + (size_t)ks * 32 * VOCABN;
#pragma unroll
      for (int c = 0; c < 4; ++c) {
        float w0 = Wk[vb[c]];
        float w1 = (Wk + 1 * VOCABN)[vb[c]];
        float w2 = (Wk + 2 * VOCABN)[vb[c]];
        float w3 = (Wk + 3 * VOCABN)[vb[c]];
        float w4 = (Wk + 4 * VOCABN)[vb[c]];
        float w5 = (Wk + 5 * VOCABN)[vb[c]];
        float w6 = (Wk + 6 * VOCABN)[vb[c]];
        float w7 = (Wk + 7 * VOCABN)[vb[c]];
        u32x4 d;
        d.x = pk2(w1, w0);
        d.y = pk2(w3, w2);
        d.z = pk2(w5, w4);
        d.w = pk2(w7, w6);
        bf16x8 bfr = __builtin_bit_cast(bf16x8, d);
#pragma unroll
        for (int mf = 0; mf < 4; ++mf)
          acc[c][mf] = __builtin_amdgcn_mfma_f32_16x16x32_bf16(
              afr[mf], bfr, acc[c][mf], 0, 0, 0);
      }
    }
#pragma unroll
    for (int c = 0; c < 4; ++c) {
      if (!val[c]) continue;
      int col = LOk + fc[c] * 16 + l15;
#pragma unroll
      for (int mf = 0; mf < 4; ++mf)
#pragma unroll
        for (int r = 0; r < 4; ++r) {
          float z = acc[c][mf][r] + biasv[c];
          int i = mf * 4 + r;
          if (tc[i] == col) ztgt[rows_sh[mf * 16 + lg * 4 + r]] = z;
          float nm = fmaxf(mM[i], z);
          sS[i] = sS[i] * __expf(mM[i] - nm) + __expf(z - nm);
          mM[i] = nm;
        }
    }
  }
#pragma unroll
  for (int i = 0; i < 16; ++i) {
    float m = mM[i], s = sS[i];
#pragma unroll
    for (int off = 1; off < 16; off <<= 1) {
      float m2 = __shfl_xor(m, off, 64);
      float s2 = __shfl_xor(s, off, 64);
      float nm = fmaxf(m, m2);
      s = s * __expf(m - nm) + s2 * __expf(m2 - nm);
      m = nm;
    }
    mM[i] = m; sS[i] = s;
  }
  if (l15 == 0) {
#pragma unroll
    for (int mf = 0; mf < 4; ++mf)
#pragma unroll
      for (int r = 0; r < 4; ++r) {
        redm[wv][mf * 16 + lg * 4 + r] = mM[mf * 4 + r];
        reds[wv][mf * 16 + lg * 4 + r] = sS[mf * 4 + r];
      }
  }
  __syncthreads();
  if (tid < MTILE) {
    float m = redm[0][tid], s = reds[0][tid];
#pragma unroll
    for (int w = 1; w < 4; ++w) {
      float m2 = redm[w][tid], s2 = reds[w][tid];
      float nm = fmaxf(m, m2);
      s = s * __expf(m - nm) + s2 * __expf(m2 - nm);
      m = nm;
    }
    pm[(NSOFF + ns) * NROWS + base + tid] = m;
    ps[(NSOFF + ns) * NROWS + base + tid] = s;
  }
}

// ---------------- kernel D: merge partials -> nll ----------------
__global__ __launch_bounds__(256) void combine_kernel(
    const int* __restrict__ cnt, const int* __restrict__ lists,
    const float* __restrict__ pm, const float* __restrict__ ps,
    const float* __restrict__ cll, const float* __restrict__ ztgt,
    float* __restrict__ out) {
  int t = blockIdx.x * 256 + threadIdx.x;
  if (t >= 3 * NROWS) return;
  int k = t / NROWS, slot = t % NROWS;
  if (slot >= cnt[k]) return;
  int row = lists[k * NROWS + slot];
  int NSk = (k == 0) ? 2 : ((k == 1) ? 8 : 40);
  int NSO = (k == 0) ? 0 : ((k == 1) ? 2 : 10);
  float m = -INFINITY, s = 0.f;
  for (int ns = 0; ns < NSk; ++ns) {
    float m2 = pm[(NSO + ns) * NROWS + slot];
    float s2 = ps[(NSO + ns) * NROWS + slot];
    float nm = fmaxf(m, m2);
    s = s * __expf(m - nm) + s2 * __expf(m2 - nm);
    m = nm;
  }
  float lse = m + __logf(s);
  out[row] = -(cll[row] + ztgt[row] - lse);
}

extern "C" void kernel_launch(void* const* d_in, const int* in_sizes, int n_in,
                              void* d_out, int out_size, void* d_ws, size_t ws_size,
                              hipStream_t stream) {
  (void)in_sizes; (void)n_in; (void)out_size;
  const float* x  = (const float*)d_in[0];
  const int*   y  = (const int*)d_in[1];
  const float* cw = (const float*)d_in[2];
  const float* cb = (const float*)d_in[3];
  const float* W  = (const float*)d_in[4];
  const float* lb = (const float*)d_in[5];
  float* out = (float*)d_out;

  char* ws = (char*)d_ws;
  int* cnt     = (int*)(ws + 0);          // 16 B
  int* lists   = (int*)(ws + 16);         // 49152 B
  float* cll   = (float*)(ws + 49168);    // 16384 B
  float* ztgt  = (float*)(ws + 65552);    // 16384 B
  float* pm    = (float*)(ws + 81936);    // 819200 B
  float* ps    = (float*)(ws + 901136);   // 819200 B  -> 1720336 B
  u32x4* Wb    = (u32x4*)(ws + 1720336);  // 51200000 B -> 52920336 B total
  const size_t WS_NEED = 52920336u;

  hipMemsetAsync(cnt, 0, 16, stream);
  group_rows_kernel<<<(NROWS + 255) / 256, 256, 0, stream>>>(y, cnt, lists);
  cll_kernel<<<NROWS / 4, 256, 0, stream>>>(x, y, cw, cb, cll);
  dim3 tg(NROWS / MTILE, MAXNS, 3);
  if (ws_size >= WS_NEED) {
    packW_kernel<<<12500, 256, 0, stream>>>(W, Wb);
    tail_mfma_packed<<<tg, 256, 0, stream>>>(x, y, Wb, lb, cnt, lists, pm, ps, ztgt);
  } else {
    tail_mfma_fb<<<tg, 256, 0, stream>>>(x, y, W, lb, cnt, lists, pm, ps, ztgt);
  }
  combine_kernel<<<(3 * NROWS + 255) / 256, 256, 0, stream>>>(cnt, lists, pm, ps, cll, ztgt, out);
}

// Round 4
// 537.359 us; speedup vs baseline: 11.1349x; 1.5060x over previous
//
#include <hip/hip_runtime.h>
#include <math.h>

#define VOCABN 50000
#define HIDN 512
#define NROWS 4096
#define MTILE 64
#define FPB 64
#define MAXNS 40
#define ASLOTS 4480   // padded grouped-slot space for Ab (>= 4096 + 3*127)

typedef __attribute__((ext_vector_type(8))) short bf16x8;
typedef __attribute__((ext_vector_type(4))) float f32x4;
typedef __attribute__((ext_vector_type(4))) unsigned u32x4;

// pack two fp32 into 2 bf16 (truncate): low16 = bf16(lo), high16 = bf16(hi)
__device__ __forceinline__ unsigned pk2(float hi, float lo) {
  return __builtin_amdgcn_perm(__builtin_bit_cast(unsigned, hi),
                               __builtin_bit_cast(unsigned, lo),
                               0x07060302u);
}

__device__ __forceinline__ void gload_lds16(const void* g, void* l) {
  __builtin_amdgcn_global_load_lds(
      (const __attribute__((address_space(1))) void*)g,
      (__attribute__((address_space(3))) void*)l, 16, 0, 0);
}

// ---------------- kernel A: bucket rows by cluster ----------------
__global__ __launch_bounds__(256) void group_rows_kernel(
    const int* __restrict__ y, int* __restrict__ cnt, int* __restrict__ lists) {
  int r = blockIdx.x * 256 + threadIdx.x;
  if (r >= NROWS) return;
  int yy = y[r];
  int k = (yy < 2000) ? 0 : ((yy < 10000) ? 1 : 2);
  int pos = atomicAdd(&cnt[k], 1);
  lists[k * NROWS + pos] = r;
}

// ---------------- kernel B: cluster-head log-softmax (per row) ----------------
__global__ __launch_bounds__(256) void cll_kernel(
    const float* __restrict__ x, const int* __restrict__ y,
    const float* __restrict__ cw, const float* __restrict__ cb,
    float* __restrict__ cll) {
  int wv = threadIdx.x >> 6, lane = threadIdx.x & 63;
  int row = blockIdx.x * 4 + wv;
  if (row >= NROWS) return;
  const float* xr = x + (size_t)((row >> 10) * 1025 + (row & 1023)) * HIDN;
  float4 v0 = *reinterpret_cast<const float4*>(xr + lane * 8);
  float4 v1 = *reinterpret_cast<const float4*>(xr + lane * 8 + 4);
  float xs[8] = {v0.x, v0.y, v0.z, v0.w, v1.x, v1.y, v1.z, v1.w};
  float a0 = 0.f, a1 = 0.f, a2 = 0.f;
#pragma unroll
  for (int u = 0; u < 8; ++u) {
    int h = lane * 8 + u;
    a0 = fmaf(xs[u], cw[h * 3 + 0], a0);
    a1 = fmaf(xs[u], cw[h * 3 + 1], a1);
    a2 = fmaf(xs[u], cw[h * 3 + 2], a2);
  }
#pragma unroll
  for (int off = 32; off; off >>= 1) {
    a0 += __shfl_xor(a0, off, 64);
    a1 += __shfl_xor(a1, off, 64);
    a2 += __shfl_xor(a2, off, 64);
  }
  if (lane == 0) {
    a0 += cb[0]; a1 += cb[1]; a2 += cb[2];
    float m3 = fmaxf(a0, fmaxf(a1, a2));
    float lse = m3 + __logf(__expf(a0 - m3) + __expf(a1 - m3) + __expf(a2 - m3));
    int yy = y[row];
    float sel = (yy < 2000) ? a0 : ((yy < 10000) ? a1 : a2);
    cll[row] = sel - lse;
  }
}

// ---------------- pack W: fp32 [k][col] -> bf16 [kt][col][oct] (16B octet groups) ----------
// Wb2 byte offset ((kt*VOCABN + col)*8 + oct)*16 holds bf16 of W[kt*64+oct*8+j][col], j=0..7
__global__ __launch_bounds__(256) void packW2_kernel(
    const float* __restrict__ W, char* __restrict__ Wb2) {
  int col = blockIdx.x * 256 + threadIdx.x;
  if (col >= VOCABN) return;
#pragma unroll
  for (int kt = 0; kt < 8; ++kt) {
#pragma unroll
    for (int oct = 0; oct < 8; ++oct) {
      const float* wp = W + (size_t)(kt * 64 + oct * 8) * VOCABN + col;
      float w0 = wp[0 * (size_t)VOCABN];
      float w1 = wp[1 * (size_t)VOCABN];
      float w2 = wp[2 * (size_t)VOCABN];
      float w3 = wp[3 * (size_t)VOCABN];
      float w4 = wp[4 * (size_t)VOCABN];
      float w5 = wp[5 * (size_t)VOCABN];
      float w6 = wp[6 * (size_t)VOCABN];
      float w7 = wp[7 * (size_t)VOCABN];
      u32x4 d;
      d.x = pk2(w1, w0);
      d.y = pk2(w3, w2);
      d.z = pk2(w5, w4);
      d.w = pk2(w7, w6);
      *reinterpret_cast<u32x4*>(Wb2 + ((size_t)(kt * VOCABN + col) * 8 + oct) * 16) = d;
    }
  }
}

// ---------------- pack A: gathered grouped rows -> bf16 [kt][gslot][oct] ----------------
__global__ __launch_bounds__(256) void packA_kernel(
    const float* __restrict__ x, const int* __restrict__ cnt,
    const int* __restrict__ lists, char* __restrict__ Ab) {
  int gslot = blockIdx.x * 32 + (threadIdx.x >> 3);
  int oct = threadIdx.x & 7;
  int c0 = cnt[0], c1 = cnt[1], c2 = cnt[2];
  int p0 = (c0 + 127) & ~127, p1 = (c1 + 127) & ~127, p2 = (c2 + 127) & ~127;
  int k, slot, count;
  if (gslot < p0)                { k = 0; slot = gslot;           count = c0; }
  else if (gslot < p0 + p1)      { k = 1; slot = gslot - p0;      count = c1; }
  else if (gslot < p0 + p1 + p2) { k = 2; slot = gslot - p0 - p1; count = c2; }
  else return;
  int r = (count > 0) ? lists[k * NROWS + min(slot, count - 1)] : 0;
  const float* xr = x + (size_t)((r >> 10) * 1025 + (r & 1023)) * HIDN;
#pragma unroll
  for (int kt = 0; kt < 8; ++kt) {
    float4 a = *reinterpret_cast<const float4*>(xr + kt * 64 + oct * 8);
    float4 b = *reinterpret_cast<const float4*>(xr + kt * 64 + oct * 8 + 4);
    u32x4 d;
    d.x = pk2(a.y, a.x);
    d.y = pk2(a.w, a.z);
    d.z = pk2(b.y, b.x);
    d.w = pk2(b.w, b.z);
    *reinterpret_cast<u32x4*>(Ab + ((size_t)kt * ASLOTS + gslot) * 128 + oct * 16) = d;
  }
}

// ---------------- main GEMM + online-LSE kernel (m97-style 128x128 tile) ----------------
__global__ __launch_bounds__(256, 2) void gemm_lse_kernel(
    const char* __restrict__ Ab, const char* __restrict__ Wb2,
    const float* __restrict__ lb, const int* __restrict__ cnt,
    const int* __restrict__ lists, const int* __restrict__ y,
    float* __restrict__ pm, float* __restrict__ ps, float* __restrict__ ztgt) {
  const int k = blockIdx.z;
  const int count = cnt[k];
  const int slot0 = blockIdx.x * 128;
  if (slot0 >= count) return;
  const int NCH = (k == 0) ? 16 : ((k == 1) ? 63 : 313);
  const int ns = blockIdx.y;
  if (ns >= NCH) return;
  const int LOk = (k == 0) ? 0 : ((k == 1) ? 2000 : 10000);
  const int HIk = (k == 0) ? 2000 : ((k == 1) ? 10000 : VOCABN);
  const int NSOFF = (k == 0) ? 0 : ((k == 1) ? 16 : 79);
  const int col0 = LOk + ns * 128;
  const int p0 = (cnt[0] + 127) & ~127, p1 = (cnt[1] + 127) & ~127;
  const int gbase = (k == 0) ? 0 : ((k == 1) ? p0 : p0 + p1);

  __shared__ __align__(16) char As[16384];
  __shared__ __align__(16) char Bs[16384];
  __shared__ float redm[2][128];
  __shared__ float reds[2][128];
  __shared__ int rows_sh[128];
  __shared__ int tgt_sh[128];

  const int tid = threadIdx.x;
  const int lane = tid & 63;
  const int wv = tid >> 6;
  const int wr = wv >> 1, wc = wv & 1;
  const int l15 = lane & 15, lg = lane >> 4;

  if (tid < 128) {
    int r = lists[k * NROWS + min(slot0 + tid, count - 1)];
    rows_sh[tid] = r;
    tgt_sh[tid] = y[r];
  }

  const char* Abase = Ab + (size_t)(gbase + slot0) * 128;
  const char* Bbase = Wb2 + (size_t)col0 * 128;

  f32x4 acc[4][4];
#pragma unroll
  for (int mi = 0; mi < 4; ++mi)
#pragma unroll
    for (int ni = 0; ni < 4; ++ni) acc[mi][ni] = (f32x4){0.f, 0.f, 0.f, 0.f};

  for (int kt = 0; kt < 8; ++kt) {
    __syncthreads();  // previous tile fully consumed (and rows_sh visible at kt=0)
    const char* Ak = Abase + (size_t)kt * (ASLOTS * 128);
    const char* Bk = Bbase + (size_t)kt * ((size_t)VOCABN * 128);
#pragma unroll
    for (int i = 0; i < 4; ++i) {
      int off = i * 4096 + tid * 16;
      gload_lds16(Ak + off, As + off);
      gload_lds16(Bk + off, Bs + off);
    }
    __syncthreads();  // vmcnt(0) drain: tiles ready
#pragma unroll
    for (int ks2 = 0; ks2 < 2; ++ks2) {
      bf16x8 af[4], bf[4];
#pragma unroll
      for (int mi = 0; mi < 4; ++mi)
        af[mi] = *reinterpret_cast<const bf16x8*>(
            As + (wr * 64 + mi * 16 + l15) * 128 + (ks2 * 4 + lg) * 16);
#pragma unroll
      for (int ni = 0; ni < 4; ++ni)
        bf[ni] = *reinterpret_cast<const bf16x8*>(
            Bs + (wc * 64 + ni * 16 + l15) * 128 + (ks2 * 4 + lg) * 16);
#pragma unroll
      for (int mi = 0; mi < 4; ++mi)
#pragma unroll
        for (int ni = 0; ni < 4; ++ni)
          acc[mi][ni] = __builtin_amdgcn_mfma_f32_16x16x32_bf16(
              af[mi], bf[ni], acc[mi][ni], 0, 0, 0);
    }
  }

  // ---- epilogue: bias, boundary mask, target capture, per-row online LSE ----
  const int colb = col0 + wc * 64 + l15;
  float biasv[4];
#pragma unroll
  for (int ni = 0; ni < 4; ++ni) {
    int col = colb + ni * 16;
    biasv[ni] = (col < HIk) ? lb[col] : 0.f;
  }
  float mrow[16], srow[16];
#pragma unroll
  for (int mi = 0; mi < 4; ++mi) {
#pragma unroll
    for (int r = 0; r < 4; ++r) {
      int i = mi * 4 + r;
      int rowl = wr * 64 + mi * 16 + lg * 4 + r;
      int tgt = tgt_sh[rowl];
      float m = -INFINITY, s = 0.f;
#pragma unroll
      for (int ni = 0; ni < 4; ++ni) {
        int col = colb + ni * 16;
        if (col < HIk) {
          float z = acc[mi][ni][r] + biasv[ni];
          if (col == tgt) ztgt[rows_sh[rowl]] = z;
          float nm = fmaxf(m, z);
          s = s * __expf(m - nm) + __expf(z - nm);
          m = nm;
        }
      }
      mrow[i] = m; srow[i] = s;
    }
  }
  // reduce across the 16 column lanes (l15) of each lg group
#pragma unroll
  for (int i = 0; i < 16; ++i) {
    float m = mrow[i], s = srow[i];
#pragma unroll
    for (int off = 1; off < 16; off <<= 1) {
      float m2 = __shfl_xor(m, off, 64);
      float s2 = __shfl_xor(s, off, 64);
      float nm = fmaxf(m, m2);
      float e1 = (m == -INFINITY) ? 0.f : __expf(m - nm);
      float e2 = (m2 == -INFINITY) ? 0.f : __expf(m2 - nm);
      s = s * e1 + s2 * e2;
      m = nm;
    }
    mrow[i] = m; srow[i] = s;
  }
  if (l15 == 0) {
#pragma unroll
    for (int mi = 0; mi < 4; ++mi)
#pragma unroll
      for (int r = 0; r < 4; ++r) {
        int rowl = wr * 64 + mi * 16 + lg * 4 + r;
        redm[wc][rowl] = mrow[mi * 4 + r];
        reds[wc][rowl] = srow[mi * 4 + r];
      }
  }
  __syncthreads();
  if (tid < 128) {
    float m = redm[0][tid], s = reds[0][tid];
    float m2 = redm[1][tid], s2 = reds[1][tid];
    float nm = fmaxf(m, m2);
    float e1 = (m == -INFINITY) ? 0.f : __expf(m - nm);
    float e2 = (m2 == -INFINITY) ? 0.f : __expf(m2 - nm);
    pm[(size_t)(NSOFF + ns) * NROWS + slot0 + tid] = nm;
    ps[(size_t)(NSOFF + ns) * NROWS + slot0 + tid] = s * e1 + s2 * e2;
  }
}

// ---------------- combine (new 128-col chunking) ----------------
__global__ __launch_bounds__(256) void combine2_kernel(
    const int* __restrict__ cnt, const int* __restrict__ lists,
    const float* __restrict__ pm, const float* __restrict__ ps,
    const float* __restrict__ cll, const float* __restrict__ ztgt,
    float* __restrict__ out) {
  int t = blockIdx.x * 256 + threadIdx.x;
  if (t >= 3 * NROWS) return;
  int k = t / NROWS, slot = t % NROWS;
  if (slot >= cnt[k]) return;
  int row = lists[k * NROWS + slot];
  int NCH = (k == 0) ? 16 : ((k == 1) ? 63 : 313);
  int NSOFF = (k == 0) ? 0 : ((k == 1) ? 16 : 79);
  float m = -INFINITY, s = 0.f;
  for (int ns = 0; ns < NCH; ++ns) {
    float m2 = pm[(size_t)(NSOFF + ns) * NROWS + slot];
    float s2 = ps[(size_t)(NSOFF + ns) * NROWS + slot];
    float nm = fmaxf(m, m2);
    float e1 = (m == -INFINITY) ? 0.f : __expf(m - nm);
    float e2 = (m2 == -INFINITY) ? 0.f : __expf(m2 - nm);
    s = s * e1 + s2 * e2;
    m = nm;
  }
  out[row] = -(cll[row] + ztgt[row] - (m + __logf(s)));
}

// ---------------- fallback (round-2 proven path, low ws need) ----------------
__global__ __launch_bounds__(256, 2) void tail_mfma_fb(
    const float* __restrict__ x, const int* __restrict__ y,
    const float* __restrict__ W, const float* __restrict__ lb,
    const int* __restrict__ cnt, const int* __restrict__ lists,
    float* __restrict__ pm, float* __restrict__ ps, float* __restrict__ ztgt) {
  const int k = blockIdx.z;
  const int NSk = (k == 0) ? 2 : ((k == 1) ? 8 : 40);
  const int ns = blockIdx.y;
  if (ns >= NSk) return;
  const int count = cnt[k];
  const int base = blockIdx.x * MTILE;
  if (base >= count) return;
  const int LOk   = (k == 0) ? 0 : ((k == 1) ? 2000 : 10000);
  const int NFRAG = ((k == 0) ? 2000 : ((k == 1) ? 8000 : 40000)) >> 4;
  const int NSOFF = (k == 0) ? 0 : ((k == 1) ? 2 : 10);
  const int flo = ns * FPB;
  const int fhi = min(NFRAG, flo + FPB);
  const int tid = threadIdx.x;
  const int lane = tid & 63;
  const int wv = tid >> 6;
  const int l15 = lane & 15;
  const int lg = lane >> 4;

  __shared__ int rows_sh[MTILE];
  __shared__ int tgt_sh[MTILE];
  __shared__ float redm[4][MTILE];
  __shared__ float reds[4][MTILE];

  if (tid < MTILE) {
    int r = lists[k * NROWS + min(base + tid, count - 1)];
    rows_sh[tid] = r;
    tgt_sh[tid] = y[r];
  }
  __syncthreads();

  const float4* xq[4];
#pragma unroll
  for (int mf = 0; mf < 4; ++mf) {
    int r = rows_sh[mf * 16 + l15];
    xq[mf] = reinterpret_cast<const float4*>(
                 x + (size_t)((r >> 10) * 1025 + (r & 1023)) * HIDN) + lg * 2;
  }
  int tc[16];
#pragma unroll
  for (int mf = 0; mf < 4; ++mf)
#pragma unroll
    for (int r = 0; r < 4; ++r) tc[mf * 4 + r] = tgt_sh[mf * 16 + lg * 4 + r];

  float mM[16], sS[16];
#pragma unroll
  for (int i = 0; i < 16; ++i) { mM[i] = -INFINITY; sS[i] = 0.f; }
  const unsigned kg_off = (unsigned)(lg * 8) * VOCABN;

  for (int f0 = flo + wv; f0 < fhi; f0 += 16) {
    int fc[4];
    bool val[4];
    unsigned vb[4];
    float biasv[4];
#pragma unroll
    for (int c = 0; c < 4; ++c) {
      int f = f0 + 4 * c;
      val[c] = (f < fhi);
      if (!val[c]) f = fhi - 1;
      fc[c] = f;
      unsigned col = (unsigned)(LOk + f * 16 + l15);
      vb[c] = kg_off + col;
      biasv[c] = lb[col];
    }
    f32x4 acc[4][4];
#pragma unroll
    for (int c = 0; c < 4; ++c)
#pragma unroll
      for (int mf = 0; mf < 4; ++mf) acc[c][mf] = (f32x4){0.f, 0.f, 0.f, 0.f};

    for (int ks = 0; ks < 16; ++ks) {
      bf16x8 afr[4];
#pragma unroll
      for (int mf = 0; mf < 4; ++mf) {
        float4 x0 = xq[mf][ks * 8];
        float4 x1 = xq[mf][ks * 8 + 1];
        u32x4 d;
        d.x = pk2(x0.y, x0.x);
        d.y = pk2(x0.w, x0.z);
        d.z = pk2(x1.y, x1.x);
        d.w = pk2(x1.w, x1.z);
        afr[mf] = __builtin_bit_cast(bf16x8, d);
      }
      const float* Wk = W + (size_t)ks * 32 * VOCABN;
#pragma unroll
      for (int c = 0; c < 4; ++c) {
        float w0 = Wk[vb[c]];
        float w1 = (Wk + 1 * VOCABN)[vb[c]];
        float w2 = (Wk + 2 * VOCABN)[vb[c]];
        float w3 = (Wk + 3 * VOCABN)[vb[c]];
        float w4 = (Wk + 4 * VOCABN)[vb[c]];
        float w5 = (Wk + 5 * VOCABN)[vb[c]];
        float w6 = (Wk + 6 * VOCABN)[vb[c]];
        float w7 = (Wk + 7 * VOCABN)[vb[c]];
        u32x4 d;
        d.x = pk2(w1, w0);
        d.y = pk2(w3, w2);
        d.z = pk2(w5, w4);
        d.w = pk2(w7, w6);
        bf16x8 bfr = __builtin_bit_cast(bf16x8, d);
#pragma unroll
        for (int mf = 0; mf < 4; ++mf)
          acc[c][mf] = __builtin_amdgcn_mfma_f32_16x16x32_bf16(
              afr[mf], bfr, acc[c][mf], 0, 0, 0);
      }
    }
#pragma unroll
    for (int c = 0; c < 4; ++c) {
      if (!val[c]) continue;
      int col = LOk + fc[c] * 16 + l15;
#pragma unroll
      for (int mf = 0; mf < 4; ++mf)
#pragma unroll
        for (int r = 0; r < 4; ++r) {
          float z = acc[c][mf][r] + biasv[c];
          int i = mf * 4 + r;
          if (tc[i] == col) ztgt[rows_sh[mf * 16 + lg * 4 + r]] = z;
          float nm = fmaxf(mM[i], z);
          sS[i] = sS[i] * __expf(mM[i] - nm) + __expf(z - nm);
          mM[i] = nm;
        }
    }
  }
#pragma unroll
  for (int i = 0; i < 16; ++i) {
    float m = mM[i], s = sS[i];
#pragma unroll
    for (int off = 1; off < 16; off <<= 1) {
      float m2 = __shfl_xor(m, off, 64);
      float s2 = __shfl_xor(s, off, 64);
      float nm = fmaxf(m, m2);
      s = s * __expf(m - nm) + s2 * __expf(m2 - nm);
      m = nm;
    }
    mM[i] = m; sS[i] = s;
  }
  if (l15 == 0) {
#pragma unroll
    for (int mf = 0; mf < 4; ++mf)
#pragma unroll
      for (int r = 0; r < 4; ++r) {
        redm[wv][mf * 16 + lg * 4 + r] = mM[mf * 4 + r];
        reds[wv][mf * 16 + lg * 4 + r] = sS[mf * 4 + r];
      }
  }
  __syncthreads();
  if (tid < MTILE) {
    float m = redm[0][tid], s = reds[0][tid];
#pragma unroll
    for (int w = 1; w < 4; ++w) {
      float m2 = redm[w][tid], s2 = reds[w][tid];
      float nm = fmaxf(m, m2);
      s = s * __expf(m - nm) + s2 * __expf(m2 - nm);
      m = nm;
    }
    pm[(NSOFF + ns) * NROWS + base + tid] = m;
    ps[(NSOFF + ns) * NROWS + base + tid] = s;
  }
}

__global__ __launch_bounds__(256) void combine_fb_kernel(
    const int* __restrict__ cnt, const int* __restrict__ lists,
    const float* __restrict__ pm, const float* __restrict__ ps,
    const float* __restrict__ cll, const float* __restrict__ ztgt,
    float* __restrict__ out) {
  int t = blockIdx.x * 256 + threadIdx.x;
  if (t >= 3 * NROWS) return;
  int k = t / NROWS, slot = t % NROWS;
  if (slot >= cnt[k]) return;
  int row = lists[k * NROWS + slot];
  int NSk = (k == 0) ? 2 : ((k == 1) ? 8 : 40);
  int NSO = (k == 0) ? 0 : ((k == 1) ? 2 : 10);
  float m = -INFINITY, s = 0.f;
  for (int ns = 0; ns < NSk; ++ns) {
    float m2 = pm[(NSO + ns) * NROWS + slot];
    float s2 = ps[(NSO + ns) * NROWS + slot];
    float nm = fmaxf(m, m2);
    float e1 = (m == -INFINITY) ? 0.f : __expf(m - nm);
    float e2 = (m2 == -INFINITY) ? 0.f : __expf(m2 - nm);
    s = s * e1 + s2 * e2;
    m = nm;
  }
  out[row] = -(cll[row] + ztgt[row] - (m + __logf(s)));
}

extern "C" void kernel_launch(void* const* d_in, const int* in_sizes, int n_in,
                              void* d_out, int out_size, void* d_ws, size_t ws_size,
                              hipStream_t stream) {
  (void)in_sizes; (void)n_in; (void)out_size;
  const float* x  = (const float*)d_in[0];
  const int*   y  = (const int*)d_in[1];
  const float* cw = (const float*)d_in[2];
  const float* cb = (const float*)d_in[3];
  const float* W  = (const float*)d_in[4];
  const float* lb = (const float*)d_in[5];
  float* out = (float*)d_out;

  char* ws = (char*)d_ws;
  int*   cnt   = (int*)(ws + 0);           // 1024
  int*   lists = (int*)(ws + 1024);        // 49152  -> 50176
  float* cll   = (float*)(ws + 50176);     // 16384  -> 66560
  float* ztgt  = (float*)(ws + 66560);     // 16384  -> 82944
  float* pm    = (float*)(ws + 82944);     // 392*4096*4 = 6422528 -> 6505472
  float* ps    = (float*)(ws + 6505472);   // 6422528 -> 12928000
  char*  Ab    = ws + 12928000;            // 8*4480*128 = 4587520 -> 17515520
  char*  Wb2   = ws + 17515520;            // (8*50000+64)*128 = 51208192 -> 68723712
  const size_t WS_NEED = 68723712u;

  hipMemsetAsync(cnt, 0, 16, stream);
  group_rows_kernel<<<(NROWS + 255) / 256, 256, 0, stream>>>(y, cnt, lists);
  cll_kernel<<<NROWS / 4, 256, 0, stream>>>(x, y, cw, cb, cll);
  if (ws_size >= WS_NEED) {
    packW2_kernel<<<(VOCABN + 255) / 256, 256, 0, stream>>>(W, Wb2);
    packA_kernel<<<ASLOTS / 32, 256, 0, stream>>>(x, cnt, lists, Ab);
    dim3 tg(NROWS / 128, 313, 3);
    gemm_lse_kernel<<<tg, 256, 0, stream>>>(Ab, Wb2, lb, cnt, lists, y, pm, ps, ztgt);
    combine2_kernel<<<(3 * NROWS + 255) / 256, 256, 0, stream>>>(
        cnt, lists, pm, ps, cll, ztgt, out);
  } else {
    dim3 tg(NROWS / MTILE, MAXNS, 3);
    tail_mfma_fb<<<tg, 256, 0, stream>>>(x, y, W, lb, cnt, lists, pm, ps, ztgt);
    combine_fb_kernel<<<(3 * NROWS + 255) / 256, 256, 0, stream>>>(
        cnt, lists, pm, ps, cll, ztgt, out);
  }
}

// Round 5
// 467.462 us; speedup vs baseline: 12.7998x; 1.1495x over previous
//
#include <hip/hip_runtime.h>
#include <math.h>

#define VOCABN 50000
#define HIDN 512
#define NROWS 4096
#define MTILE 64
#define FPB 64
#define MAXNS 40
#define ASLOTS 4480   // padded grouped-slot space for Ab (>= 4096 + 3*127)

typedef __attribute__((ext_vector_type(8))) short bf16x8;
typedef __attribute__((ext_vector_type(4))) float f32x4;
typedef __attribute__((ext_vector_type(4))) unsigned u32x4;

// pack two fp32 into 2 bf16 (truncate): low16 = bf16(lo), high16 = bf16(hi)
__device__ __forceinline__ unsigned pk2(float hi, float lo) {
  return __builtin_amdgcn_perm(__builtin_bit_cast(unsigned, hi),
                               __builtin_bit_cast(unsigned, lo),
                               0x07060302u);
}

__device__ __forceinline__ void gload_lds16(const void* g, void* l) {
  __builtin_amdgcn_global_load_lds(
      (const __attribute__((address_space(1))) void*)g,
      (__attribute__((address_space(3))) void*)l, 16, 0, 0);
}

// ---------------- kernel A: bucket rows by cluster ----------------
__global__ __launch_bounds__(256) void group_rows_kernel(
    const int* __restrict__ y, int* __restrict__ cnt, int* __restrict__ lists) {
  int r = blockIdx.x * 256 + threadIdx.x;
  if (r >= NROWS) return;
  int yy = y[r];
  int k = (yy < 2000) ? 0 : ((yy < 10000) ? 1 : 2);
  int pos = atomicAdd(&cnt[k], 1);
  lists[k * NROWS + pos] = r;
}

// ---------------- kernel B: cluster-head log-softmax (per row) ----------------
__global__ __launch_bounds__(256) void cll_kernel(
    const float* __restrict__ x, const int* __restrict__ y,
    const float* __restrict__ cw, const float* __restrict__ cb,
    float* __restrict__ cll) {
  int wv = threadIdx.x >> 6, lane = threadIdx.x & 63;
  int row = blockIdx.x * 4 + wv;
  if (row >= NROWS) return;
  const float* xr = x + (size_t)((row >> 10) * 1025 + (row & 1023)) * HIDN;
  float4 v0 = *reinterpret_cast<const float4*>(xr + lane * 8);
  float4 v1 = *reinterpret_cast<const float4*>(xr + lane * 8 + 4);
  float xs[8] = {v0.x, v0.y, v0.z, v0.w, v1.x, v1.y, v1.z, v1.w};
  float a0 = 0.f, a1 = 0.f, a2 = 0.f;
#pragma unroll
  for (int u = 0; u < 8; ++u) {
    int h = lane * 8 + u;
    a0 = fmaf(xs[u], cw[h * 3 + 0], a0);
    a1 = fmaf(xs[u], cw[h * 3 + 1], a1);
    a2 = fmaf(xs[u], cw[h * 3 + 2], a2);
  }
#pragma unroll
  for (int off = 32; off; off >>= 1) {
    a0 += __shfl_xor(a0, off, 64);
    a1 += __shfl_xor(a1, off, 64);
    a2 += __shfl_xor(a2, off, 64);
  }
  if (lane == 0) {
    a0 += cb[0]; a1 += cb[1]; a2 += cb[2];
    float m3 = fmaxf(a0, fmaxf(a1, a2));
    float lse = m3 + __logf(__expf(a0 - m3) + __expf(a1 - m3) + __expf(a2 - m3));
    int yy = y[row];
    float sel = (yy < 2000) ? a0 : ((yy < 10000) ? a1 : a2);
    cll[row] = sel - lse;
  }
}

// ---------------- pack W: fp32 [k][col] -> bf16 [kt][col][oct^swz] ----------
// Wb2 byte ((kt*VOCABN + col)*8 + (oct ^ (col&7)))*16 holds bf16 of
// W[kt*64+oct*8+j][col], j=0..7   (XOR swizzle keyed on col&7)
__global__ __launch_bounds__(256) void packW2_kernel(
    const float* __restrict__ W, char* __restrict__ Wb2) {
  int col = blockIdx.x * 256 + threadIdx.x;
  if (col >= VOCABN) return;
  int swz = col & 7;
#pragma unroll
  for (int kt = 0; kt < 8; ++kt) {
#pragma unroll
    for (int oct = 0; oct < 8; ++oct) {
      const float* wp = W + (size_t)(kt * 64 + oct * 8) * VOCABN + col;
      float w0 = wp[0 * (size_t)VOCABN];
      float w1 = wp[1 * (size_t)VOCABN];
      float w2 = wp[2 * (size_t)VOCABN];
      float w3 = wp[3 * (size_t)VOCABN];
      float w4 = wp[4 * (size_t)VOCABN];
      float w5 = wp[5 * (size_t)VOCABN];
      float w6 = wp[6 * (size_t)VOCABN];
      float w7 = wp[7 * (size_t)VOCABN];
      u32x4 d;
      d.x = pk2(w1, w0);
      d.y = pk2(w3, w2);
      d.z = pk2(w5, w4);
      d.w = pk2(w7, w6);
      *reinterpret_cast<u32x4*>(
          Wb2 + ((size_t)(kt * VOCABN + col) * 8 + (oct ^ swz)) * 16) = d;
    }
  }
}

// ---------------- pack A: grouped rows -> bf16 [kt][gslot][oct^swz] ----------------
__global__ __launch_bounds__(256) void packA_kernel(
    const float* __restrict__ x, const int* __restrict__ cnt,
    const int* __restrict__ lists, char* __restrict__ Ab) {
  int gslot = blockIdx.x * 32 + (threadIdx.x >> 3);
  int oct = threadIdx.x & 7;
  int c0 = cnt[0], c1 = cnt[1], c2 = cnt[2];
  int p0 = (c0 + 127) & ~127, p1 = (c1 + 127) & ~127, p2 = (c2 + 127) & ~127;
  int k, slot, count;
  if (gslot < p0)                { k = 0; slot = gslot;           count = c0; }
  else if (gslot < p0 + p1)      { k = 1; slot = gslot - p0;      count = c1; }
  else if (gslot < p0 + p1 + p2) { k = 2; slot = gslot - p0 - p1; count = c2; }
  else return;
  int r = (count > 0) ? lists[k * NROWS + min(slot, count - 1)] : 0;
  const float* xr = x + (size_t)((r >> 10) * 1025 + (r & 1023)) * HIDN;
  int swz = gslot & 7;
#pragma unroll
  for (int kt = 0; kt < 8; ++kt) {
    float4 a = *reinterpret_cast<const float4*>(xr + kt * 64 + oct * 8);
    float4 b = *reinterpret_cast<const float4*>(xr + kt * 64 + oct * 8 + 4);
    u32x4 d;
    d.x = pk2(a.y, a.x);
    d.y = pk2(a.w, a.z);
    d.z = pk2(b.y, b.x);
    d.w = pk2(b.w, b.z);
    *reinterpret_cast<u32x4*>(
        Ab + ((size_t)kt * ASLOTS + gslot) * 128 + (oct ^ swz) * 16) = d;
  }
}

// ---------------- main GEMM + online-LSE kernel (128x128 tile, swizzled LDS) ----------------
__global__ __launch_bounds__(256, 4) void gemm_lse_kernel(
    const char* __restrict__ Ab, const char* __restrict__ Wb2,
    const float* __restrict__ lb, const int* __restrict__ cnt,
    const int* __restrict__ lists, const int* __restrict__ y,
    float* __restrict__ pm, float* __restrict__ ps, float* __restrict__ ztgt) {
  const int k = blockIdx.z;
  const int count = cnt[k];
  const int slot0 = blockIdx.x * 128;
  if (slot0 >= count) return;
  const int NCH = (k == 0) ? 16 : ((k == 1) ? 63 : 313);
  const int ns = blockIdx.y;
  if (ns >= NCH) return;
  const int LOk = (k == 0) ? 0 : ((k == 1) ? 2000 : 10000);
  const int HIk = (k == 0) ? 2000 : ((k == 1) ? 10000 : VOCABN);
  const int NSOFF = (k == 0) ? 0 : ((k == 1) ? 16 : 79);
  const int col0 = LOk + ns * 128;
  const int p0 = (cnt[0] + 127) & ~127, p1 = (cnt[1] + 127) & ~127;
  const int gbase = (k == 0) ? 0 : ((k == 1) ? p0 : p0 + p1);

  __shared__ __align__(16) char As[16384];
  __shared__ __align__(16) char Bs[16384];
  __shared__ float redm[2][128];
  __shared__ float reds[2][128];
  __shared__ int rows_sh[128];
  __shared__ int tgt_sh[128];

  const int tid = threadIdx.x;
  const int lane = tid & 63;
  const int wv = tid >> 6;
  const int wr = wv >> 1, wc = wv & 1;
  const int l15 = lane & 15, lg = lane >> 4;
  const int swz = l15 & 7;   // row ≡ l15 (mod 8) for all fragment reads

  if (tid < 128) {
    int r = lists[k * NROWS + min(slot0 + tid, count - 1)];
    rows_sh[tid] = r;
    tgt_sh[tid] = y[r];
  }

  const char* Abase = Ab + (size_t)(gbase + slot0) * 128;
  const char* Bbase = Wb2 + (size_t)col0 * 128;

  f32x4 acc[4][4];
#pragma unroll
  for (int mi = 0; mi < 4; ++mi)
#pragma unroll
    for (int ni = 0; ni < 4; ++ni) acc[mi][ni] = (f32x4){0.f, 0.f, 0.f, 0.f};

  for (int kt = 0; kt < 8; ++kt) {
    __syncthreads();  // previous tile fully consumed (and rows_sh visible at kt=0)
    const char* Ak = Abase + (size_t)kt * (ASLOTS * 128);
    const char* Bk = Bbase + (size_t)kt * ((size_t)VOCABN * 128);
#pragma unroll
    for (int i = 0; i < 4; ++i) {
      int off = i * 4096 + tid * 16;
      gload_lds16(Ak + off, As + off);
      gload_lds16(Bk + off, Bs + off);
    }
    __syncthreads();  // vmcnt(0) drain: tiles ready
#pragma unroll
    for (int ks2 = 0; ks2 < 2; ++ks2) {
      bf16x8 af[4], bf[4];
#pragma unroll
      for (int mi = 0; mi < 4; ++mi)
        af[mi] = *reinterpret_cast<const bf16x8*>(
            As + (wr * 64 + mi * 16 + l15) * 128 + ((ks2 * 4 + lg) ^ swz) * 16);
#pragma unroll
      for (int ni = 0; ni < 4; ++ni)
        bf[ni] = *reinterpret_cast<const bf16x8*>(
            Bs + (wc * 64 + ni * 16 + l15) * 128 + ((ks2 * 4 + lg) ^ swz) * 16);
#pragma unroll
      for (int mi = 0; mi < 4; ++mi)
#pragma unroll
        for (int ni = 0; ni < 4; ++ni)
          acc[mi][ni] = __builtin_amdgcn_mfma_f32_16x16x32_bf16(
              af[mi], bf[ni], acc[mi][ni], 0, 0, 0);
    }
  }

  // ---- epilogue: bias, boundary mask, target capture, per-row online LSE ----
  const int colb = col0 + wc * 64 + l15;
  float biasv[4];
#pragma unroll
  for (int ni = 0; ni < 4; ++ni) {
    int col = colb + ni * 16;
    biasv[ni] = (col < HIk) ? lb[col] : 0.f;
  }
  float mrow[16], srow[16];
#pragma unroll
  for (int mi = 0; mi < 4; ++mi) {
#pragma unroll
    for (int r = 0; r < 4; ++r) {
      int i = mi * 4 + r;
      int rowl = wr * 64 + mi * 16 + lg * 4 + r;
      int tgt = tgt_sh[rowl];
      float m = -INFINITY, s = 0.f;
#pragma unroll
      for (int ni = 0; ni < 4; ++ni) {
        int col = colb + ni * 16;
        if (col < HIk) {
          float z = acc[mi][ni][r] + biasv[ni];
          if (col == tgt) ztgt[rows_sh[rowl]] = z;
          float nm = fmaxf(m, z);
          s = s * __expf(m - nm) + __expf(z - nm);
          m = nm;
        }
      }
      mrow[i] = m; srow[i] = s;
    }
  }
  // reduce across the 16 column lanes (l15) of each lg group
#pragma unroll
  for (int i = 0; i < 16; ++i) {
    float m = mrow[i], s = srow[i];
#pragma unroll
    for (int off = 1; off < 16; off <<= 1) {
      float m2 = __shfl_xor(m, off, 64);
      float s2 = __shfl_xor(s, off, 64);
      float nm = fmaxf(m, m2);
      float e1 = (m == -INFINITY) ? 0.f : __expf(m - nm);
      float e2 = (m2 == -INFINITY) ? 0.f : __expf(m2 - nm);
      s = s * e1 + s2 * e2;
      m = nm;
    }
    mrow[i] = m; srow[i] = s;
  }
  if (l15 == 0) {
#pragma unroll
    for (int mi = 0; mi < 4; ++mi)
#pragma unroll
      for (int r = 0; r < 4; ++r) {
        int rowl = wr * 64 + mi * 16 + lg * 4 + r;
        redm[wc][rowl] = mrow[mi * 4 + r];
        reds[wc][rowl] = srow[mi * 4 + r];
      }
  }
  __syncthreads();
  if (tid < 128) {
    float m = redm[0][tid], s = reds[0][tid];
    float m2 = redm[1][tid], s2 = reds[1][tid];
    float nm = fmaxf(m, m2);
    float e1 = (m == -INFINITY) ? 0.f : __expf(m - nm);
    float e2 = (m2 == -INFINITY) ? 0.f : __expf(m2 - nm);
    pm[(size_t)(NSOFF + ns) * NROWS + slot0 + tid] = nm;
    ps[(size_t)(NSOFF + ns) * NROWS + slot0 + tid] = s * e1 + s2 * e2;
  }
}

// ---------------- combine (128-col chunking) ----------------
__global__ __launch_bounds__(256) void combine2_kernel(
    const int* __restrict__ cnt, const int* __restrict__ lists,
    const float* __restrict__ pm, const float* __restrict__ ps,
    const float* __restrict__ cll, const float* __restrict__ ztgt,
    float* __restrict__ out) {
  int t = blockIdx.x * 256 + threadIdx.x;
  if (t >= 3 * NROWS) return;
  int k = t / NROWS, slot = t % NROWS;
  if (slot >= cnt[k]) return;
  int row = lists[k * NROWS + slot];
  int NCH = (k == 0) ? 16 : ((k == 1) ? 63 : 313);
  int NSOFF = (k == 0) ? 0 : ((k == 1) ? 16 : 79);
  float m = -INFINITY, s = 0.f;
  for (int ns = 0; ns < NCH; ++ns) {
    float m2 = pm[(size_t)(NSOFF + ns) * NROWS + slot];
    float s2 = ps[(size_t)(NSOFF + ns) * NROWS + slot];
    float nm = fmaxf(m, m2);
    float e1 = (m == -INFINITY) ? 0.f : __expf(m - nm);
    float e2 = (m2 == -INFINITY) ? 0.f : __expf(m2 - nm);
    s = s * e1 + s2 * e2;
    m = nm;
  }
  out[row] = -(cll[row] + ztgt[row] - (m + __logf(s)));
}

// ---------------- fallback (round-2 proven path, low ws need) ----------------
__global__ __launch_bounds__(256, 2) void tail_mfma_fb(
    const float* __restrict__ x, const int* __restrict__ y,
    const float* __restrict__ W, const float* __restrict__ lb,
    const int* __restrict__ cnt, const int* __restrict__ lists,
    float* __restrict__ pm, float* __restrict__ ps, float* __restrict__ ztgt) {
  const int k = blockIdx.z;
  const int NSk = (k == 0) ? 2 : ((k == 1) ? 8 : 40);
  const int ns = blockIdx.y;
  if (ns >= NSk) return;
  const int count = cnt[k];
  const int base = blockIdx.x * MTILE;
  if (base >= count) return;
  const int LOk   = (k == 0) ? 0 : ((k == 1) ? 2000 : 10000);
  const int NFRAG = ((k == 0) ? 2000 : ((k == 1) ? 8000 : 40000)) >> 4;
  const int NSOFF = (k == 0) ? 0 : ((k == 1) ? 2 : 10);
  const int flo = ns * FPB;
  const int fhi = min(NFRAG, flo + FPB);
  const int tid = threadIdx.x;
  const int lane = tid & 63;
  const int wv = tid >> 6;
  const int l15 = lane & 15;
  const int lg = lane >> 4;

  __shared__ int rows_sh[MTILE];
  __shared__ int tgt_sh[MTILE];
  __shared__ float redm[4][MTILE];
  __shared__ float reds[4][MTILE];

  if (tid < MTILE) {
    int r = lists[k * NROWS + min(base + tid, count - 1)];
    rows_sh[tid] = r;
    tgt_sh[tid] = y[r];
  }
  __syncthreads();

  const float4* xq[4];
#pragma unroll
  for (int mf = 0; mf < 4; ++mf) {
    int r = rows_sh[mf * 16 + l15];
    xq[mf] = reinterpret_cast<const float4*>(
                 x + (size_t)((r >> 10) * 1025 + (r & 1023)) * HIDN) + lg * 2;
  }
  int tc[16];
#pragma unroll
  for (int mf = 0; mf < 4; ++mf)
#pragma unroll
    for (int r = 0; r < 4; ++r) tc[mf * 4 + r] = tgt_sh[mf * 16 + lg * 4 + r];

  float mM[16], sS[16];
#pragma unroll
  for (int i = 0; i < 16; ++i) { mM[i] = -INFINITY; sS[i] = 0.f; }
  const unsigned kg_off = (unsigned)(lg * 8) * VOCABN;

  for (int f0 = flo + wv; f0 < fhi; f0 += 16) {
    int fc[4];
    bool val[4];
    unsigned vb[4];
    float biasv[4];
#pragma unroll
    for (int c = 0; c < 4; ++c) {
      int f = f0 + 4 * c;
      val[c] = (f < fhi);
      if (!val[c]) f = fhi - 1;
      fc[c] = f;
      unsigned col = (unsigned)(LOk + f * 16 + l15);
      vb[c] = kg_off + col;
      biasv[c] = lb[col];
    }
    f32x4 acc[4][4];
#pragma unroll
    for (int c = 0; c < 4; ++c)
#pragma unroll
      for (int mf = 0; mf < 4; ++mf) acc[c][mf] = (f32x4){0.f, 0.f, 0.f, 0.f};

    for (int ks = 0; ks < 16; ++ks) {
      bf16x8 afr[4];
#pragma unroll
      for (int mf = 0; mf < 4; ++mf) {
        float4 x0 = xq[mf][ks * 8];
        float4 x1 = xq[mf][ks * 8 + 1];
        u32x4 d;
        d.x = pk2(x0.y, x0.x);
        d.y = pk2(x0.w, x0.z);
        d.z = pk2(x1.y, x1.x);
        d.w = pk2(x1.w, x1.z);
        afr[mf] = __builtin_bit_cast(bf16x8, d);
      }
      const float* Wk = W + (size_t)ks * 32 * VOCABN;
#pragma unroll
      for (int c = 0; c < 4; ++c) {
        float w0 = Wk[vb[c]];
        float w1 = (Wk + 1 * VOCABN)[vb[c]];
        float w2 = (Wk + 2 * VOCABN)[vb[c]];
        float w3 = (Wk + 3 * VOCABN)[vb[c]];
        float w4 = (Wk + 4 * VOCABN)[vb[c]];
        float w5 = (Wk + 5 * VOCABN)[vb[c]];
        float w6 = (Wk + 6 * VOCABN)[vb[c]];
        float w7 = (Wk + 7 * VOCABN)[vb[c]];
        u32x4 d;
        d.x = pk2(w1, w0);
        d.y = pk2(w3, w2);
        d.z = pk2(w5, w4);
        d.w = pk2(w7, w6);
        bf16x8 bfr = __builtin_bit_cast(bf16x8, d);
#pragma unroll
        for (int mf = 0; mf < 4; ++mf)
          acc[c][mf] = __builtin_amdgcn_mfma_f32_16x16x32_bf16(
              afr[mf], bfr, acc[c][mf], 0, 0, 0);
      }
    }
#pragma unroll
    for (int c = 0; c < 4; ++c) {
      if (!val[c]) continue;
      int col = LOk + fc[c] * 16 + l15;
#pragma unroll
      for (int mf = 0; mf < 4; ++mf)
#pragma unroll
        for (int r = 0; r < 4; ++r) {
          float z = acc[c][mf][r] + biasv[c];
          int i = mf * 4 + r;
          if (tc[i] == col) ztgt[rows_sh[mf * 16 + lg * 4 + r]] = z;
          float nm = fmaxf(mM[i], z);
          sS[i] = sS[i] * __expf(mM[i] - nm) + __expf(z - nm);
          mM[i] = nm;
        }
    }
  }
#pragma unroll
  for (int i = 0; i < 16; ++i) {
    float m = mM[i], s = sS[i];
#pragma unroll
    for (int off = 1; off < 16; off <<= 1) {
      float m2 = __shfl_xor(m, off, 64);
      float s2 = __shfl_xor(s, off, 64);
      float nm = fmaxf(m, m2);
      s = s * __expf(m - nm) + s2 * __expf(m2 - nm);
      m = nm;
    }
    mM[i] = m; sS[i] = s;
  }
  if (l15 == 0) {
#pragma unroll
    for (int mf = 0; mf < 4; ++mf)
#pragma unroll
      for (int r = 0; r < 4; ++r) {
        redm[wv][mf * 16 + lg * 4 + r] = mM[mf * 4 + r];
        reds[wv][mf * 16 + lg * 4 + r] = sS[mf * 4 + r];
      }
  }
  __syncthreads();
  if (tid < MTILE) {
    float m = redm[0][tid], s = reds[0][tid];
#pragma unroll
    for (int w = 1; w < 4; ++w) {
      float m2 = redm[w][tid], s2 = reds[w][tid];
      float nm = fmaxf(m, m2);
      s = s * __expf(m - nm) + s2 * __expf(m2 - nm);
      m = nm;
    }
    pm[(NSOFF + ns) * NROWS + base + tid] = m;
    ps[(NSOFF + ns) * NROWS + base + tid] = s;
  }
}

__global__ __launch_bounds__(256) void combine_fb_kernel(
    const int* __restrict__ cnt, const int* __restrict__ lists,
    const float* __restrict__ pm, const float* __restrict__ ps,
    const float* __restrict__ cll, const float* __restrict__ ztgt,
    float* __restrict__ out) {
  int t = blockIdx.x * 256 + threadIdx.x;
  if (t >= 3 * NROWS) return;
  int k = t / NROWS, slot = t % NROWS;
  if (slot >= cnt[k]) return;
  int row = lists[k * NROWS + slot];
  int NSk = (k == 0) ? 2 : ((k == 1) ? 8 : 40);
  int NSO = (k == 0) ? 0 : ((k == 1) ? 2 : 10);
  float m = -INFINITY, s = 0.f;
  for (int ns = 0; ns < NSk; ++ns) {
    float m2 = pm[(NSO + ns) * NROWS + slot];
    float s2 = ps[(NSO + ns) * NROWS + slot];
    float nm = fmaxf(m, m2);
    float e1 = (m == -INFINITY) ? 0.f : __expf(m - nm);
    float e2 = (m2 == -INFINITY) ? 0.f : __expf(m2 - nm);
    s = s * e1 + s2 * e2;
    m = nm;
  }
  out[row] = -(cll[row] + ztgt[row] - (m + __logf(s)));
}

extern "C" void kernel_launch(void* const* d_in, const int* in_sizes, int n_in,
                              void* d_out, int out_size, void* d_ws, size_t ws_size,
                              hipStream_t stream) {
  (void)in_sizes; (void)n_in; (void)out_size;
  const float* x  = (const float*)d_in[0];
  const int*   y  = (const int*)d_in[1];
  const float* cw = (const float*)d_in[2];
  const float* cb = (const float*)d_in[3];
  const float* W  = (const float*)d_in[4];
  const float* lb = (const float*)d_in[5];
  float* out = (float*)d_out;

  char* ws = (char*)d_ws;
  int*   cnt   = (int*)(ws + 0);           // 1024
  int*   lists = (int*)(ws + 1024);        // 49152  -> 50176
  float* cll   = (float*)(ws + 50176);     // 16384  -> 66560
  float* ztgt  = (float*)(ws + 66560);     // 16384  -> 82944
  float* pm    = (float*)(ws + 82944);     // 392*4096*4 = 6422528 -> 6505472
  float* ps    = (float*)(ws + 6505472);   // 6422528 -> 12928000
  char*  Ab    = ws + 12928000;            // 8*4480*128 = 4587520 -> 17515520
  char*  Wb2   = ws + 17515520;            // (8*50000+64)*128 = 51208192 -> 68723712
  const size_t WS_NEED = 68723712u;

  hipMemsetAsync(cnt, 0, 16, stream);
  group_rows_kernel<<<(NROWS + 255) / 256, 256, 0, stream>>>(y, cnt, lists);
  cll_kernel<<<NROWS / 4, 256, 0, stream>>>(x, y, cw, cb, cll);
  if (ws_size >= WS_NEED) {
    packW2_kernel<<<(VOCABN + 255) / 256, 256, 0, stream>>>(W, Wb2);
    packA_kernel<<<ASLOTS / 32, 256, 0, stream>>>(x, cnt, lists, Ab);
    dim3 tg(NROWS / 128, 313, 3);
    gemm_lse_kernel<<<tg, 256, 0, stream>>>(Ab, Wb2, lb, cnt, lists, y, pm, ps, ztgt);
    combine2_kernel<<<(3 * NROWS + 255) / 256, 256, 0, stream>>>(
        cnt, lists, pm, ps, cll, ztgt, out);
  } else {
    dim3 tg(NROWS / MTILE, MAXNS, 3);
    tail_mfma_fb<<<tg, 256, 0, stream>>>(x, y, W, lb, cnt, lists, pm, ps, ztgt);
    combine_fb_kernel<<<(3 * NROWS + 255) / 256, 256, 0, stream>>>(
        cnt, lists, pm, ps, cll, ztgt, out);
  }
}